// Round 6
// baseline (492.049 us; speedup 1.0000x reference)
//
#include <hip/hip_runtime.h>
#include <math.h>

#define TT 84
#define BB 96
#define GB 6            // batches per group
#define NG 16           // groups (NG*GB == BB)
#define NL 10
#define NTOK (TT*BB)
#define XPS 37          // xp LDS row stride (floats); 37 % 32 == 5 -> <=2-way bank overlap

// Gate-argument pre-scaling folded into weights/biases:
//  r,z rows scaled by -log2(e)   -> sigm(a) = rcp(1 + exp2(arg))
//  n rows scaled by -2*log2(e)   -> tanh(x) = 2*rcp(1 + exp2(arg)) - 1
#define S_RZ (-1.4426950408889634f)
#define S_N  (-2.8853900817779268f)

__device__ __forceinline__ float frcp(float x)  { return __builtin_amdgcn_rcpf(x); }
__device__ __forceinline__ float fexp2(float x) { return __builtin_amdgcn_exp2f(x); }

// ---------------- layer-0 projection: emb gather + E=400 dot (pre-scaled) ----
__global__ __launch_bounds__(256) void proj0_kernel(
    const int* __restrict__ x, const float* __restrict__ emb,
    const float* __restrict__ wih0, const float* __restrict__ bih0,
    float* __restrict__ xp, unsigned int* __restrict__ bar)
{
    if (blockIdx.x == 0 && threadIdx.x == 0) bar[0] = 0u;  // re-zero grid barrier
    __shared__ float4 xrow[32][100];   // 32 tokens x 400 floats
    const int tok0 = blockIdx.x * 32;
    for (int u = threadIdx.x; u < 32*100; u += 256) {
        int tk = u / 100, i4 = u % 100;
        int row = x[tok0 + tk];
        xrow[tk][i4] = ((const float4*)emb)[row*100 + i4];
    }
    __syncthreads();
    const int g64 = threadIdx.x & 63;
    const int q   = threadIdx.x >> 6;          // 0..3, 8 tokens each
    if (g64 >= 60) return;
    const int dir = g64 / 30, gg = g64 % 30;
    const float sc = (gg < 20) ? S_RZ : S_N;
    const float bias = bih0[dir*30 + gg];
    float acc[8];
    #pragma unroll
    for (int c = 0; c < 8; ++c) acc[c] = bias;
    const float4* w4 = ((const float4*)wih0) + (dir*30 + gg)*100;
    for (int i4 = 0; i4 < 100; ++i4) {
        float4 w = w4[i4];
        #pragma unroll
        for (int c = 0; c < 8; ++c) {
            float4 xv = xrow[q*8 + c][i4];
            acc[c] += w.x*xv.x + w.y*xv.y + w.z*xv.z + w.w*xv.w;
        }
    }
    #pragma unroll
    for (int c = 0; c < 8; ++c) {
        int tok = tok0 + q*8 + c;
        int t = tok / BB, b = tok % BB;
        xp[((size_t)((dir*TT + t)*BB + b))*30 + gg] = acc[c]*sc;
    }
}

// ---------------- GRU cell: pre-scaled args, h from exchange reads -----------
__device__ __forceinline__ float gru_cell(
    float xr, float xz, float xn,
    float4 ha, float4 hb, float2 hc,
    const float* wr, const float* wz, const float* wn,
    float bhr, float bhz, float bhn, float& hown)
{
    float hr0 = fmaf(wr[0], ha.x, bhr), hr1 = wr[1]*ha.y;
    float hz0 = fmaf(wz[0], ha.x, bhz), hz1 = wz[1]*ha.y;
    float hn0 = fmaf(wn[0], ha.x, bhn), hn1 = wn[1]*ha.y;
    hr0 = fmaf(wr[2], ha.z, hr0); hr1 = fmaf(wr[3], ha.w, hr1);
    hz0 = fmaf(wz[2], ha.z, hz0); hz1 = fmaf(wz[3], ha.w, hz1);
    hn0 = fmaf(wn[2], ha.z, hn0); hn1 = fmaf(wn[3], ha.w, hn1);
    hr0 = fmaf(wr[4], hb.x, hr0); hr1 = fmaf(wr[5], hb.y, hr1);
    hz0 = fmaf(wz[4], hb.x, hz0); hz1 = fmaf(wz[5], hb.y, hz1);
    hn0 = fmaf(wn[4], hb.x, hn0); hn1 = fmaf(wn[5], hb.y, hn1);
    hr0 = fmaf(wr[6], hb.z, hr0); hr1 = fmaf(wr[7], hb.w, hr1);
    hz0 = fmaf(wz[6], hb.z, hz0); hz1 = fmaf(wz[7], hb.w, hz1);
    hn0 = fmaf(wn[6], hb.z, hn0); hn1 = fmaf(wn[7], hb.w, hn1);
    hr0 = fmaf(wr[8], hc.x, hr0); hr1 = fmaf(wr[9], hc.y, hr1);
    hz0 = fmaf(wz[8], hc.x, hz0); hz1 = fmaf(wz[9], hc.y, hz1);
    hn0 = fmaf(wn[8], hc.x, hn0); hn1 = fmaf(wn[9], hc.y, hn1);
    float r = frcp(1.f + fexp2(xr + hr0 + hr1));
    float z = frcp(1.f + fexp2(xz + hz0 + hz1));
    float an = fmaf(r, hn0 + hn1, xn);
    float n  = fmaf(2.f, frcp(1.f + fexp2(an)), -1.f);
    float hnew = n + z*(hown - n);
    hown = hnew;
    return hnew;
}

__device__ __forceinline__ void waitflag(int* f, int needed)
{
    int fv = __hip_atomic_load(f, __ATOMIC_ACQUIRE, __HIP_MEMORY_SCOPE_WORKGROUP);
    while (fv < needed)
        fv = __hip_atomic_load(f, __ATOMIC_ACQUIRE, __HIP_MEMORY_SCOPE_WORKGROUP);
}

// ---------------- mega: all 10 layers + head, 16 blocks x 256 ----------------
// waves 0/1: fwd/bwd GRU scan (latency-critical).
// waves 2/3: fwd/bwd gate-input producers (proj of prev layer's act -> LDS xp).
__global__ __launch_bounds__(256, 1) void mega_kernel(
    const float* __restrict__ xp0,
    const float* __restrict__ whh0, const float* __restrict__ bhh0,
    const float* __restrict__ wih,  const float* __restrict__ bih,
    const float* __restrict__ whh,  const float* __restrict__ bhh,
    const float* __restrict__ lin_w, const float* __restrict__ lin_b,
    float* __restrict__ actA, float* __restrict__ actB,
    unsigned int* __restrict__ bar, float* __restrict__ out)
{
    __shared__ float xpS[2*TT*GB*XPS];   // 149,184 B (feat aliases this after scans)
    __shared__ float hbuf[2][GB][12];    // 576 B exchange buffer
    __shared__ int   flagsS[NL][2];      // producer progress per layer/dir

    const int tid  = threadIdx.x;
    const int wave = tid >> 6;
    const int lane = tid & 63;
    int bl = lane / 10; if (bl > 5) bl = 5;
    int j  = lane - bl*10; if (j > 9) j = 9;
    const bool act_ln = (lane < 60);
    const int grp = blockIdx.x;
    const int b   = grp*GB + bl;

    if (tid < NL*2) ((int*)flagsS)[tid] = 0;
    __syncthreads();

    const int dir = wave & 1;            // scan dir for waves 0/1; producer dir for 2/3
    const int dt  = dir ? -1 : 1;
    const int t0  = dir ? TT-1 : 0;

    #pragma unroll 1
    for (int l = 0; l < NL; ++l) {
        if (wave < 2) {
            // ================= consumer: GRU scan =================
            const float* whL = (l==0) ? (whh0 + dir*300) : (whh + (size_t)((l-1)*2+dir)*300);
            const float* bhL = (l==0) ? (bhh0 + dir*30)  : (bhh + (size_t)((l-1)*2+dir)*30);
            float* actW = (l & 1) ? actB : actA;
            int* flag = &flagsS[l][dir];

            float wr[10], wz[10], wn[10];
            {
                const float2* p0 = (const float2*)(whL + j*10);
                const float2* p1 = (const float2*)(whL + (10+j)*10);
                const float2* p2 = (const float2*)(whL + (20+j)*10);
                #pragma unroll
                for (int q = 0; q < 5; ++q) {
                    float2 a = p0[q]; wr[2*q]=a.x*S_RZ; wr[2*q+1]=a.y*S_RZ;
                    float2 c = p1[q]; wz[2*q]=c.x*S_RZ; wz[2*q+1]=c.y*S_RZ;
                    float2 d = p2[q]; wn[2*q]=d.x*S_N;  wn[2*q+1]=d.y*S_N;
                }
            }
            const float bhr = bhL[j]*S_RZ, bhz = bhL[10+j]*S_RZ, bhn = bhL[20+j]*S_N;

            float4 ha = {0,0,0,0}, hb4 = {0,0,0,0};
            float2 hc2 = {0,0};
            float hown = 0.f;

            // prologue: gate inputs for rows 0 and 1
            waitflag(flag, 1);
            int base0 = ((dir*TT + t0)*GB + bl)*XPS;
            float xc0 = xpS[base0+j], xc1 = xpS[base0+10+j], xc2 = xpS[base0+20+j];
            waitflag(flag, 2);
            int base1 = ((dir*TT + (t0+dt))*GB + bl)*XPS;
            float xn0 = xpS[base1+j], xn1 = xpS[base1+10+j], xn2 = xpS[base1+20+j];

            const float4* hp = (const float4*)&hbuf[dir][bl][0];
            int t = t0;
            #pragma unroll 2
            for (int s = 0; s < TT; ++s) {
                float hnew = gru_cell(xc0,xc1,xc2, ha,hb4,hc2, wr,wz,wn, bhr,bhz,bhn, hown);
                hbuf[dir][bl][j] = hnew;        // exchange write
                ha  = hp[0];                    // exchange reads (2x b128 + b64)
                hb4 = hp[1];
                hc2 = ((const float2*)hp)[4];
                __builtin_amdgcn_sched_barrier(0);
                if (act_ln) actW[(size_t)(t*BB + b)*20 + dir*10 + j] = hnew;
                int sp = s + 2;
                int needed = (sp+1 > TT) ? TT : sp+1;
                waitflag(flag, needed);
                int tp = t0 + dt*sp; tp = tp < 0 ? 0 : (tp > TT-1 ? TT-1 : tp);
                int bp = ((dir*TT + tp)*GB + bl)*XPS;
                float p0 = xpS[bp+j], p1 = xpS[bp+10+j], p2 = xpS[bp+20+j];
                xc0 = xn0; xc1 = xn1; xc2 = xn2;
                xn0 = p0;  xn1 = p1;  xn2 = p2;
                t += dt;
            }
        } else {
            // ================= producer: gate-input projection =================
            int* flag = &flagsS[l][dir];
            if (l == 0) {
                // copy pre-scaled xp0 (global) -> xpS
                const float* xg = xp0 + (size_t)dir*TT*BB*30;
                int t = t0;
                int g0 = (t*BB + b)*30;
                float a0 = xg[g0+j], a1 = xg[g0+10+j], a2 = xg[g0+20+j];
                #pragma unroll 1
                for (int srow = 0; srow < TT; ++srow) {
                    int tn = (srow == TT-1) ? t : t + dt;
                    int gn = (tn*BB + b)*30;
                    float n0 = xg[gn+j], n1 = xg[gn+10+j], n2 = xg[gn+20+j];
                    int bo = ((dir*TT + t)*GB + bl)*XPS;
                    xpS[bo+j] = a0; xpS[bo+10+j] = a1; xpS[bo+20+j] = a2;
                    if (lane == 0)
                        __hip_atomic_store(flag, srow+1, __ATOMIC_RELEASE, __HIP_MEMORY_SCOPE_WORKGROUP);
                    a0 = n0; a1 = n1; a2 = n2; t = tn;
                }
            } else {
                const float* wiL = wih + (size_t)((l-1)*2 + dir)*600;
                const float* biL = bih + (size_t)((l-1)*2 + dir)*30;
                float wpr[20], wpz[20], wpn[20];
                {
                    const float4* p0 = (const float4*)(wiL + j*20);
                    const float4* p1 = (const float4*)(wiL + (10+j)*20);
                    const float4* p2 = (const float4*)(wiL + (20+j)*20);
                    #pragma unroll
                    for (int q = 0; q < 5; ++q) {
                        float4 a = p0[q]; wpr[4*q]=a.x*S_RZ; wpr[4*q+1]=a.y*S_RZ; wpr[4*q+2]=a.z*S_RZ; wpr[4*q+3]=a.w*S_RZ;
                        float4 c = p1[q]; wpz[4*q]=c.x*S_RZ; wpz[4*q+1]=c.y*S_RZ; wpz[4*q+2]=c.z*S_RZ; wpz[4*q+3]=c.w*S_RZ;
                        float4 d = p2[q]; wpn[4*q]=d.x*S_N;  wpn[4*q+1]=d.y*S_N;  wpn[4*q+2]=d.z*S_N;  wpn[4*q+3]=d.w*S_N;
                    }
                }
                const float bir = biL[j]*S_RZ, biz = biL[10+j]*S_RZ, bin = biL[20+j]*S_N;
                const float* actR = (l & 1) ? actA : actB;   // prev layer's output
                float4 A[5], Bv[5];
                int t = t0;
                {
                    const float4* ap = (const float4*)(actR + (size_t)(t*BB + b)*20);
                    #pragma unroll
                    for (int q = 0; q < 5; ++q) A[q] = ap[q];
                }
                #pragma unroll 1
                for (int srow = 0; srow < TT; ++srow) {
                    int tn = (srow == TT-1) ? t : t + dt;
                    const float4* ap = (const float4*)(actR + (size_t)(tn*BB + b)*20);
                    #pragma unroll
                    for (int q = 0; q < 5; ++q) Bv[q] = ap[q];   // prefetch next row
                    float av[20];
                    #pragma unroll
                    for (int q = 0; q < 5; ++q) {
                        av[4*q]=A[q].x; av[4*q+1]=A[q].y; av[4*q+2]=A[q].z; av[4*q+3]=A[q].w;
                    }
                    float xr = bir, xz = biz, xn = bin;
                    #pragma unroll
                    for (int c = 0; c < 20; ++c) {
                        xr = fmaf(wpr[c], av[c], xr);
                        xz = fmaf(wpz[c], av[c], xz);
                        xn = fmaf(wpn[c], av[c], xn);
                    }
                    int bo = ((dir*TT + t)*GB + bl)*XPS;
                    xpS[bo+j] = xr; xpS[bo+10+j] = xz; xpS[bo+20+j] = xn;
                    if (lane == 0)
                        __hip_atomic_store(flag, srow+1, __ATOMIC_RELEASE, __HIP_MEMORY_SCOPE_WORKGROUP);
                    #pragma unroll
                    for (int q = 0; q < 5; ++q) A[q] = Bv[q];
                    t = tn;
                }
            }
        }
        __syncthreads();
    }

    // ---- grid barrier (16 blocks, all co-resident) ----
    __threadfence();
    __syncthreads();
    if (tid == 0) {
        __hip_atomic_fetch_add(bar, 1u, __ATOMIC_ACQ_REL, __HIP_MEMORY_SCOPE_AGENT);
        while (__hip_atomic_load(bar, __ATOMIC_ACQUIRE, __HIP_MEMORY_SCOPE_AGENT) < (unsigned)NG)
            __builtin_amdgcn_s_sleep(1);
    }
    __syncthreads();
    __threadfence();

    // ---- head: rows r = grp*6 .. grp*6+5 (layer 9 output = actB) ----
    float* feat = xpS;                   // alias
    for (int u = tid; u < GB*336; u += 256) {
        int q = u / 336, v = u % 336;
        int r = grp*GB + q;
        int qq = v / 12, f = v % 12;
        int pair = r*28 + qq;           // t*32 + bb
        int t = pair / 32, bb = pair % 32;
        int jj = (f < 6) ? f : f - 6;
        float acc = (f < 6) ? 0.f : -1e30f;
        #pragma unroll
        for (int i = 0; i < 3; ++i) {
            #pragma unroll
            for (int kk = 0; kk < 3; ++kk) {
                float vv = actB[(size_t)(t*BB + bb*3 + i)*20 + jj*3 + kk];
                if (f < 6) acc += vv; else acc = fmaxf(acc, vv);
            }
        }
        feat[u] = (f < 6) ? acc*(1.f/9.f) : acc;
    }
    __syncthreads();
    if (tid < GB*19) {
        int q = tid / 19, o = tid % 19;
        int r = grp*GB + q;
        float acc = lin_b[o];
        const float* wrow = lin_w + o*336;
        const float* frow = feat + q*336;
        for (int v = 0; v < 336; ++v) acc = fmaf(frow[v], wrow[v], acc);
        out[r*19 + o] = frcp(1.f + __expf(-acc));
    }
}

extern "C" void kernel_launch(void* const* d_in, const int* in_sizes, int n_in,
                              void* d_out, int out_size, void* d_ws, size_t ws_size,
                              hipStream_t stream)
{
    const int*   x     = (const int*)  d_in[0];
    const float* emb   = (const float*)d_in[1];
    const float* wih0  = (const float*)d_in[2];
    const float* whh0  = (const float*)d_in[3];
    const float* bih0  = (const float*)d_in[4];
    const float* bhh0  = (const float*)d_in[5];
    const float* wih   = (const float*)d_in[6];
    const float* whh   = (const float*)d_in[7];
    const float* bih   = (const float*)d_in[8];
    const float* bhh   = (const float*)d_in[9];
    const float* lin_w = (const float*)d_in[10];
    const float* lin_b = (const float*)d_in[11];
    float* out = (float*)d_out;

    float* xp0  = (float*)d_ws;                    // 2*84*96*30 = 483840 floats
    float* actA = xp0 + (size_t)2*NTOK*30;         // 84*96*20   = 161280 floats
    unsigned int* bar = (unsigned int*)(actA + (size_t)NTOK*20);
    float* actB = xp0;   // aliases xp0: reused as odd-layer act buffer after layer 0

    proj0_kernel<<<252, 256, 0, stream>>>(x, emb, wih0, bih0, xp0, bar);
    mega_kernel<<<NG, 256, 0, stream>>>(xp0, whh0, bhh0, wih, bih, whh, bhh,
                                        lin_w, lin_b, actA, actB, bar, out);
}